// Round 8
// baseline (312.692 us; speedup 1.0000x reference)
//
#include <hip/hip_runtime.h>
#include <math.h>

#define N_NODES 50000
#define N_EDGES 800000
#define D 128
#define NPAD 50048   // N rounded up, keeps segments 16B-aligned
#define NBLK 196     // ceil(N_NODES/256)

typedef unsigned int uint32;
typedef __attribute__((ext_vector_type(8))) short short8;   // 8 bf16 (4 VGPRs)
typedef __attribute__((ext_vector_type(4))) float f32x4;    // MFMA C/D

__device__ __forceinline__ ushort f2bf(float f) {
    uint32 u = __float_as_uint(f);
    u = (u + 0x7fff + ((u >> 16) & 1)) >> 16;   // round-to-nearest-even
    return (ushort)u;
}
__device__ __forceinline__ float bf2f(ushort u) {
    return __uint_as_float(((uint32)u) << 16);
}

// ---------------------------------------------------------------------------
// CSR build: count (+record rank) -> local scan -> fused base add -> fill
// ---------------------------------------------------------------------------

__global__ __launch_bounds__(256) void k_count(const int* __restrict__ col,
                                               int* __restrict__ counts,
                                               int* __restrict__ rank_buf) {
    int i4 = (blockIdx.x * 256 + threadIdx.x) * 4;
    if (i4 < N_EDGES) {   // N_EDGES % 4 == 0
        int4 c = *(const int4*)(col + i4);
        int4 r;
        r.x = atomicAdd(&counts[c.x], 1);
        r.y = atomicAdd(&counts[c.y], 1);
        r.z = atomicAdd(&counts[c.z], 1);
        r.w = atomicAdd(&counts[c.w], 1);
        *(int4*)(rank_buf + i4) = r;
    }
}

__global__ __launch_bounds__(256) void k_scan_local(const int* __restrict__ counts,
                                                    int* __restrict__ offsets,
                                                    int* __restrict__ partials) {
    __shared__ int wsum[4];
    int tid = threadIdx.x;
    int i = blockIdx.x * 256 + tid;
    int v = (i < N_NODES) ? counts[i] : 0;
    int lane = tid & 63, wv = tid >> 6;
    int x = v;
    #pragma unroll
    for (int off = 1; off < 64; off <<= 1) {
        int y = __shfl_up(x, off);
        if (lane >= off) x += y;
    }
    if (lane == 63) wsum[wv] = x;
    __syncthreads();
    int b0 = wsum[0], b1 = wsum[1], b2 = wsum[2], b3 = wsum[3];
    int base = (wv > 0 ? b0 : 0) + (wv > 1 ? b1 : 0) + (wv > 2 ? b2 : 0);
    if (i < N_NODES) offsets[i] = base + x - v;
    if (tid == 255) partials[blockIdx.x] = b0 + b1 + b2 + b3;
}

__global__ __launch_bounds__(256) void k_scan_add(int* __restrict__ offsets,
                                                  const int* __restrict__ partials,
                                                  const int* __restrict__ counts,
                                                  float* __restrict__ dinv) {
    __shared__ int wsum[4];
    int tid = threadIdx.x;
    int p = (tid < (int)blockIdx.x && tid < NBLK) ? partials[tid] : 0;
    int lane = tid & 63, wv = tid >> 6;
    #pragma unroll
    for (int off = 32; off; off >>= 1) p += __shfl_down(p, off);
    if (lane == 0) wsum[wv] = p;
    __syncthreads();
    int base = wsum[0] + wsum[1] + wsum[2] + wsum[3];
    int i = blockIdx.x * 256 + tid;
    if (i < N_NODES) {
        offsets[i] += base;
        dinv[i] = rsqrtf((float)counts[i] + 1.0f);  // +1 self-loop
    }
    if (i == 0) offsets[N_NODES] = N_EDGES;
}

__global__ __launch_bounds__(256) void k_fill(const int* __restrict__ row,
                                              const int* __restrict__ col,
                                              const int* __restrict__ offsets,
                                              const int* __restrict__ rank_buf,
                                              int* __restrict__ csr_rows) {
    int i4 = (blockIdx.x * 256 + threadIdx.x) * 4;
    if (i4 < N_EDGES) {
        int4 c = *(const int4*)(col + i4);
        int4 r = *(const int4*)(rank_buf + i4);
        int4 rw = *(const int4*)(row + i4);
        csr_rows[offsets[c.x] + r.x] = rw.x;
        csr_rows[offsets[c.y] + r.y] = rw.y;
        csr_rows[offsets[c.z] + r.z] = rw.z;
        csr_rows[offsets[c.w] + r.w] = rw.w;
    }
}

// ---------------------------------------------------------------------------
// W pre-convert: wt[l][n*128+k] = bf16(W_l[k*128+n])  (3 x 16384 elems)
// ---------------------------------------------------------------------------
__global__ __launch_bounds__(256) void k_wconv(const float* __restrict__ W0,
                                               const float* __restrict__ W1,
                                               const float* __restrict__ W2,
                                               ushort* __restrict__ wt) {
    int i = blockIdx.x * 256 + threadIdx.x;    // 49152 total
    int l = i >> 14;
    int flat = i & 16383;
    int n = flat >> 7, k = flat & 127;
    const float* W = (l == 0) ? W0 : (l == 1) ? W1 : W2;
    wt[i] = f2bf(W[k * 128 + n]);   // coalesced write, gathered read (L2-hot)
}

// ---------------------------------------------------------------------------
// MFMA GEMM: hw_bf16[N,D] = bf16( dinv[.] * (h @ W) ).  One 64-row tile per
// block (782 blocks), 4 waves x 16 rows. A fragments loaded DIRECT from
// global (bf16 hb, or fp32 hf converted inline for layer 0) — no A LDS, no
// per-tile barriers. Wt staged once from pre-converted global bf16.
// As LDS used only for the wave-private epilogue transpose.
// mfma_f32_16x16x32_bf16: A[m=lane&15][k=(lane>>4)*8+j];
// B[k=(lane>>4)*8+j][n=lane&15]; D col=lane&15, row=(lane>>4)*4+reg.
// ---------------------------------------------------------------------------
#define BM 64
#define LDA 136                          // padded ushort stride
#define NTILES ((N_NODES + BM - 1) / BM) // 782

__global__ __launch_bounds__(256) void k_gemm(const float* __restrict__ hf,
                                              const ushort* __restrict__ hb,
                                              const ushort* __restrict__ wt,
                                              const float* __restrict__ dinv,
                                              ushort* __restrict__ hw) {
    __shared__ __align__(16) ushort Wt[D * LDA];    // 34.8 KB
    __shared__ __align__(16) ushort As[BM * LDA];   // 17.0 KB (epilogue only)
    int tid = threadIdx.x;
    int lane = tid & 63;
    int w = tid >> 6;
    int quad = lane >> 4;
    int m16 = lane & 15;

    // stage Wt: 128 rows x 16 chunks of 8 bf16 (16B) = 2048 chunks, 8/thread
    #pragma unroll
    for (int i = 0; i < 8; ++i) {
        int chunk = i * 256 + tid;
        int n = chunk >> 4, k16 = chunk & 15;   // 16 chunks per 128-elem row
        *(short8*)(Wt + n * LDA + k16 * 8) = *(const short8*)(wt + n * 128 + k16 * 8);
    }
    __syncthreads();   // only barrier in the kernel

    int row0 = blockIdx.x * BM;
    int arow = row0 + w * 16 + m16;

    f32x4 acc[8];
    #pragma unroll
    for (int ct = 0; ct < 8; ++ct) acc[ct] = (f32x4){0.f, 0.f, 0.f, 0.f};

    #pragma unroll
    for (int ks = 0; ks < 4; ++ks) {
        short8 a;
        if (hf) {
            if (arow < N_NODES) {
                const float4* p = (const float4*)(hf + (size_t)arow * D + ks * 32 + quad * 8);
                float4 x0 = p[0], x1 = p[1];
                a[0] = (short)f2bf(x0.x); a[1] = (short)f2bf(x0.y);
                a[2] = (short)f2bf(x0.z); a[3] = (short)f2bf(x0.w);
                a[4] = (short)f2bf(x1.x); a[5] = (short)f2bf(x1.y);
                a[6] = (short)f2bf(x1.z); a[7] = (short)f2bf(x1.w);
            } else {
                a = (short8){};
            }
        } else {
            // hb has NPAD rows: reads past N_NODES are in-bounds garbage,
            // scaled by dv=0 and never stored
            a = *(const short8*)(hb + (size_t)arow * D + ks * 32 + quad * 8);
        }
        #pragma unroll
        for (int ct = 0; ct < 8; ++ct) {
            short8 b = *(const short8*)(Wt + (ct * 16 + m16) * LDA + ks * 32 + quad * 8);
            acc[ct] = __builtin_amdgcn_mfma_f32_16x16x32_bf16(a, b, acc[ct], 0, 0, 0);
        }
    }

    // epilogue: dinv scale + bf16, transpose through wave-private As rows
    float dv[4];
    #pragma unroll
    for (int r = 0; r < 4; ++r) {
        int row = row0 + w * 16 + quad * 4 + r;
        dv[r] = (row < N_NODES) ? dinv[row] : 0.f;
    }
    #pragma unroll
    for (int ct = 0; ct < 8; ++ct) {
        #pragma unroll
        for (int r = 0; r < 4; ++r)
            As[(w * 16 + quad * 4 + r) * LDA + ct * 16 + m16] = f2bf(acc[ct][r] * dv[r]);
    }
    // store 16 rows x 128 cols: 256 chunks of 8 elems (16B), 4 iters x 64 lanes
    #pragma unroll
    for (int i = 0; i < 4; ++i) {
        int chunk = i * 64 + lane;
        int r = chunk >> 4, c8 = chunk & 15;
        int row = row0 + w * 16 + r;
        if (row < N_NODES) {
            short8 v = *(const short8*)(As + (w * 16 + r) * LDA + c8 * 8);
            *(short8*)(hw + (size_t)row * D + c8 * 8) = v;
        }
    }
}

// ---------------------------------------------------------------------------
// Aggregate (bf16 rows): one WAVE per node, 4 quarter-groups of 16 lanes.
// Quarter q handles edges j==s+q (mod 4); lane owns cols 8m..8m+7 via short8
// (16B) loads. Unroll x2 -> 8 gather chains in flight per wave.
// ---------------------------------------------------------------------------
__global__ __launch_bounds__(256) void k_agg(const ushort* __restrict__ hw,
                                             const float* __restrict__ dinv,
                                             const int* __restrict__ offsets,
                                             const int* __restrict__ csr_rows,
                                             const float* __restrict__ bias,
                                             float* __restrict__ out, int layer,
                                             ushort* __restrict__ hnext, int write_next) {
    int node = blockIdx.x * 4 + (threadIdx.x >> 6);
    int lane = threadIdx.x & 63;
    int q = lane >> 4;
    int m = lane & 15;

    float acc[8] = {};
    int s = offsets[node], e = offsets[node + 1];
    int j = s + q;
    for (; j + 4 < e; j += 8) {
        int r0 = csr_rows[j];
        int r1 = csr_rows[j + 4];
        short8 v0 = *((const short8*)(hw + (size_t)r0 * D) + m);
        short8 v1 = *((const short8*)(hw + (size_t)r1 * D) + m);
        #pragma unroll
        for (int i = 0; i < 8; ++i)
            acc[i] += bf2f((ushort)v0[i]) + bf2f((ushort)v1[i]);
    }
    for (; j < e; j += 4) {
        int r = csr_rows[j];
        short8 v = *((const short8*)(hw + (size_t)r * D) + m);
        #pragma unroll
        for (int i = 0; i < 8; ++i) acc[i] += bf2f((ushort)v[i]);
    }
    // reduce across the 4 quarters (lanes with same m)
    #pragma unroll
    for (int i = 0; i < 8; ++i) {
        acc[i] += __shfl_xor(acc[i], 16);
        acc[i] += __shfl_xor(acc[i], 32);
    }

    if (q == 0) {
        float di = dinv[node];
        short8 sv = *((const short8*)(hw + (size_t)node * D) + m);
        float4 ba = ((const float4*)bias)[2 * m];
        float4 bb = ((const float4*)bias)[2 * m + 1];
        float bv[8] = {ba.x, ba.y, ba.z, ba.w, bb.x, bb.y, bb.z, bb.w};
        float o[8];
        #pragma unroll
        for (int i = 0; i < 8; ++i)
            o[i] = tanhf(di * (acc[i] + bf2f((ushort)sv[i])) + bv[i]);
        float* op = out + ((size_t)node * 3 + layer) * D;
        ((float4*)op)[2 * m]     = make_float4(o[0], o[1], o[2], o[3]);
        ((float4*)op)[2 * m + 1] = make_float4(o[4], o[5], o[6], o[7]);
        if (write_next) {
            short8 nv;
            #pragma unroll
            for (int i = 0; i < 8; ++i) nv[i] = (short)f2bf(o[i]);
            *((short8*)(hnext + (size_t)node * D) + m) = nv;
        }
    }
}

// ---------------------------------------------------------------------------

extern "C" void kernel_launch(void* const* d_in, const int* in_sizes, int n_in,
                              void* d_out, int out_size, void* d_ws, size_t ws_size,
                              hipStream_t stream) {
    const float* x  = (const float*)d_in[0];
    const int*   ei = (const int*)d_in[1];
    const float* W0 = (const float*)d_in[2];
    const float* b0 = (const float*)d_in[3];
    const float* W1 = (const float*)d_in[4];
    const float* b1 = (const float*)d_in[5];
    const float* W2 = (const float*)d_in[6];
    const float* b2 = (const float*)d_in[7];
    float* out = (float*)d_out;

    const int* row = ei;             // edge_index[0]
    const int* col = ei + N_EDGES;   // edge_index[1]

    // workspace layout (all segments 16B-aligned)
    float*  dinv    = (float*)d_ws;                // NPAD
    int*    counts  = (int*)(dinv + NPAD);         // NPAD
    int*    offsets = counts + NPAD;               // NPAD (N+1 used)
    int*    partials= offsets + NPAD;              // 256
    ushort* wt      = (ushort*)(partials + 256);   // 3*16384 bf16 (96 KB)
    int*    rank_buf= (int*)(wt + 3 * 16384);      // N_EDGES
    int*    csr     = rank_buf + N_EDGES;          // N_EDGES
    ushort* hw      = (ushort*)(csr + N_EDGES);    // NPAD*D bf16
    ushort* hnext   = hw + (size_t)NPAD * D;       // NPAD*D bf16

    int nb_e4 = (N_EDGES / 4 + 255) / 256;         // 782

    hipMemsetAsync(counts, 0, NPAD * sizeof(int), stream);
    k_wconv<<<192, 256, 0, stream>>>(W0, W1, W2, wt);
    k_count<<<nb_e4, 256, 0, stream>>>(col, counts, rank_buf);
    k_scan_local<<<NBLK, 256, 0, stream>>>(counts, offsets, partials);
    k_scan_add<<<NBLK, 256, 0, stream>>>(offsets, partials, counts, dinv);
    k_fill<<<nb_e4, 256, 0, stream>>>(row, col, offsets, rank_buf, csr);

    int nb_agg = N_NODES / 4;   // one wave per node

    const float* bs_[3] = {b0, b1, b2};
    for (int l = 0; l < 3; ++l) {
        if (l == 0) k_gemm<<<NTILES, 256, 0, stream>>>(x, (const ushort*)nullptr, wt, dinv, hw);
        else        k_gemm<<<NTILES, 256, 0, stream>>>((const float*)nullptr, hnext, wt + l * 16384, dinv, hw);
        k_agg<<<nb_agg, 256, 0, stream>>>(hw, dinv, offsets, csr, bs_[l], out, l,
                                          hnext, l < 2 ? 1 : 0);
    }
}

// Round 9
// 306.649 us; speedup vs baseline: 1.0197x; 1.0197x over previous
//
#include <hip/hip_runtime.h>
#include <math.h>

#define N_NODES 50000
#define N_EDGES 800000
#define D 128
#define NPAD 50048   // N rounded up, keeps segments 16B-aligned
#define NBLK 196     // ceil(N_NODES/256)

typedef unsigned int uint32;
typedef __attribute__((ext_vector_type(8))) short short8;   // 8 bf16 (4 VGPRs)
typedef __attribute__((ext_vector_type(4))) float f32x4;    // MFMA C/D

__device__ __forceinline__ ushort f2bf(float f) {
    uint32 u = __float_as_uint(f);
    u = (u + 0x7fff + ((u >> 16) & 1)) >> 16;   // round-to-nearest-even
    return (ushort)u;
}
__device__ __forceinline__ float bf2f(ushort u) {
    return __uint_as_float(((uint32)u) << 16);
}

// ---------------------------------------------------------------------------
// Fused: blocks 0..191 pre-convert W0/W1/W2 -> wt[l][n*128+k] (bf16, transposed)
//        blocks 192..  count edges (8/thread) + record per-edge rank
// ---------------------------------------------------------------------------
#define WCONV_BLKS 192

__global__ __launch_bounds__(256) void k_count_wconv(const int* __restrict__ col,
                                                     int* __restrict__ counts,
                                                     int* __restrict__ rank_buf,
                                                     const float* __restrict__ W0,
                                                     const float* __restrict__ W1,
                                                     const float* __restrict__ W2,
                                                     ushort* __restrict__ wt) {
    int tid = threadIdx.x;
    if (blockIdx.x < WCONV_BLKS) {
        int i = blockIdx.x * 256 + tid;    // 49152 total
        int l = i >> 14;
        int flat = i & 16383;
        int n = flat >> 7, k = flat & 127;
        const float* W = (l == 0) ? W0 : (l == 1) ? W1 : W2;
        wt[i] = f2bf(W[k * 128 + n]);
    } else {
        int i8 = ((blockIdx.x - WCONV_BLKS) * 256 + tid) * 8;
        if (i8 < N_EDGES) {   // N_EDGES % 8 == 0 -> all-or-nothing
            int4 c0 = *(const int4*)(col + i8);
            int4 c1 = *(const int4*)(col + i8 + 4);
            int4 r0, r1;
            r0.x = atomicAdd(&counts[c0.x], 1);
            r0.y = atomicAdd(&counts[c0.y], 1);
            r0.z = atomicAdd(&counts[c0.z], 1);
            r0.w = atomicAdd(&counts[c0.w], 1);
            r1.x = atomicAdd(&counts[c1.x], 1);
            r1.y = atomicAdd(&counts[c1.y], 1);
            r1.z = atomicAdd(&counts[c1.z], 1);
            r1.w = atomicAdd(&counts[c1.w], 1);
            *(int4*)(rank_buf + i8)     = r0;
            *(int4*)(rank_buf + i8 + 4) = r1;
        }
    }
}

// ---------------------------------------------------------------------------
// CSR scan: per-block local scan -> fused base-reduce + add + dinv
// ---------------------------------------------------------------------------

__global__ __launch_bounds__(256) void k_scan_local(const int* __restrict__ counts,
                                                    int* __restrict__ offsets,
                                                    int* __restrict__ partials) {
    __shared__ int wsum[4];
    int tid = threadIdx.x;
    int i = blockIdx.x * 256 + tid;
    int v = (i < N_NODES) ? counts[i] : 0;
    int lane = tid & 63, wv = tid >> 6;
    int x = v;
    #pragma unroll
    for (int off = 1; off < 64; off <<= 1) {
        int y = __shfl_up(x, off);
        if (lane >= off) x += y;
    }
    if (lane == 63) wsum[wv] = x;
    __syncthreads();
    int b0 = wsum[0], b1 = wsum[1], b2 = wsum[2], b3 = wsum[3];
    int base = (wv > 0 ? b0 : 0) + (wv > 1 ? b1 : 0) + (wv > 2 ? b2 : 0);
    if (i < N_NODES) offsets[i] = base + x - v;
    if (tid == 255) partials[blockIdx.x] = b0 + b1 + b2 + b3;
}

__global__ __launch_bounds__(256) void k_scan_add(int* __restrict__ offsets,
                                                  const int* __restrict__ partials,
                                                  const int* __restrict__ counts,
                                                  float* __restrict__ dinv) {
    __shared__ int wsum[4];
    int tid = threadIdx.x;
    int p = (tid < (int)blockIdx.x && tid < NBLK) ? partials[tid] : 0;
    int lane = tid & 63, wv = tid >> 6;
    #pragma unroll
    for (int off = 32; off; off >>= 1) p += __shfl_down(p, off);
    if (lane == 0) wsum[wv] = p;
    __syncthreads();
    int base = wsum[0] + wsum[1] + wsum[2] + wsum[3];
    int i = blockIdx.x * 256 + tid;
    if (i < N_NODES) {
        offsets[i] += base;
        dinv[i] = rsqrtf((float)counts[i] + 1.0f);  // +1 self-loop
    }
    if (i == 0) offsets[N_NODES] = N_EDGES;
}

__global__ __launch_bounds__(256) void k_fill(const int* __restrict__ row,
                                              const int* __restrict__ col,
                                              const int* __restrict__ offsets,
                                              const int* __restrict__ rank_buf,
                                              int* __restrict__ csr_rows) {
    int i8 = (blockIdx.x * 256 + threadIdx.x) * 8;
    if (i8 < N_EDGES) {
        int4 c0 = *(const int4*)(col + i8);
        int4 c1 = *(const int4*)(col + i8 + 4);
        int4 r0 = *(const int4*)(rank_buf + i8);
        int4 r1 = *(const int4*)(rank_buf + i8 + 4);
        int4 w0 = *(const int4*)(row + i8);
        int4 w1 = *(const int4*)(row + i8 + 4);
        csr_rows[offsets[c0.x] + r0.x] = w0.x;
        csr_rows[offsets[c0.y] + r0.y] = w0.y;
        csr_rows[offsets[c0.z] + r0.z] = w0.z;
        csr_rows[offsets[c0.w] + r0.w] = w0.w;
        csr_rows[offsets[c1.x] + r1.x] = w1.x;
        csr_rows[offsets[c1.y] + r1.y] = w1.y;
        csr_rows[offsets[c1.z] + r1.z] = w1.z;
        csr_rows[offsets[c1.w] + r1.w] = w1.w;
    }
}

// ---------------------------------------------------------------------------
// MFMA GEMM: hw_bf16[N,D] = bf16( dinv[.] * (h @ W) ), h fp32 with row stride
// (x: stride D; out: stride 3D). One 64-row tile per block, 4 waves x 16 rows.
// A staged to LDS with coalesced float4 reads + inline bf16 convert; Wt staged
// from pre-converted global bf16. One barrier per kernel-tile.
// mfma_f32_16x16x32_bf16: A[m=lane&15][k=(lane>>4)*8+j];
// B[k=(lane>>4)*8+j][n=lane&15]; D col=lane&15, row=(lane>>4)*4+reg.
// ---------------------------------------------------------------------------
#define BM 64
#define LDA 136                          // padded ushort stride (272 B)
#define NTILES ((N_NODES + BM - 1) / BM) // 782

__global__ __launch_bounds__(256) void k_gemm(const float* __restrict__ h, int hstride,
                                              const ushort* __restrict__ wt,
                                              const float* __restrict__ dinv,
                                              ushort* __restrict__ hw) {
    __shared__ __align__(16) ushort Wt[D * LDA];    // 34.8 KB
    __shared__ __align__(16) ushort As[BM * LDA];   // 17.4 KB
    int tid = threadIdx.x;
    int lane = tid & 63;
    int w = tid >> 6;
    int quad = lane >> 4;
    int m16 = lane & 15;
    int row0 = blockIdx.x * BM;

    // stage Wt: 128 rows x 16 chunks of 8 bf16 (16B) = 2048 chunks, 8/thread
    #pragma unroll
    for (int i = 0; i < 8; ++i) {
        int chunk = i * 256 + tid;
        int n = chunk >> 4, k16 = chunk & 15;
        *(short8*)(Wt + n * LDA + k16 * 8) = *(const short8*)(wt + n * 128 + k16 * 8);
    }
    // stage A: 64 rows x 32 float4 = 2048 float4 chunks, 8/thread, coalesced
    #pragma unroll
    for (int p = 0; p < 8; ++p) {
        int flat = p * 256 + tid;
        int r = flat >> 5, c4 = flat & 31;
        int row = row0 + r;
        ushort4 u = {0, 0, 0, 0};
        if (row < N_NODES) {
            float4 v = *(const float4*)(h + (size_t)row * hstride + c4 * 4);
            u.x = f2bf(v.x); u.y = f2bf(v.y); u.z = f2bf(v.z); u.w = f2bf(v.w);
        }
        *(ushort4*)(As + r * LDA + c4 * 4) = u;
    }
    __syncthreads();   // only barrier

    f32x4 acc[8];
    #pragma unroll
    for (int ct = 0; ct < 8; ++ct) acc[ct] = (f32x4){0.f, 0.f, 0.f, 0.f};

    #pragma unroll
    for (int ks = 0; ks < 4; ++ks) {
        short8 a = *(const short8*)(As + (w * 16 + m16) * LDA + ks * 32 + quad * 8);
        #pragma unroll
        for (int ct = 0; ct < 8; ++ct) {
            short8 b = *(const short8*)(Wt + (ct * 16 + m16) * LDA + ks * 32 + quad * 8);
            acc[ct] = __builtin_amdgcn_mfma_f32_16x16x32_bf16(a, b, acc[ct], 0, 0, 0);
        }
    }

    // epilogue: dinv scale + bf16, transpose through the wave's OWN As rows
    // (wave w reads/writes only rows 16w..16w+15 -> no barrier needed)
    float dv[4];
    #pragma unroll
    for (int r = 0; r < 4; ++r) {
        int row = row0 + w * 16 + quad * 4 + r;
        dv[r] = (row < N_NODES) ? dinv[row] : 0.f;
    }
    #pragma unroll
    for (int ct = 0; ct < 8; ++ct) {
        #pragma unroll
        for (int r = 0; r < 4; ++r)
            As[(w * 16 + quad * 4 + r) * LDA + ct * 16 + m16] = f2bf(acc[ct][r] * dv[r]);
    }
    // store 16 rows x 128 cols: 256 chunks of 8 elems (16B), 4 iters x 64 lanes
    #pragma unroll
    for (int i = 0; i < 4; ++i) {
        int chunk = i * 64 + lane;
        int r = chunk >> 4, c8 = chunk & 15;
        int row = row0 + w * 16 + r;
        if (row < N_NODES) {
            short8 v = *(const short8*)(As + (w * 16 + r) * LDA + c8 * 8);
            *(short8*)(hw + (size_t)row * D + c8 * 8) = v;
        }
    }
}

// ---------------------------------------------------------------------------
// Aggregate (bf16 rows): one WAVE per node, 4 quarter-groups of 16 lanes.
// Quarter q handles edges j==s+q (mod 4); lane owns cols 8m..8m+7 via short8
// (16B) loads. Unroll x2 -> 8 gather chains in flight per wave.
// ---------------------------------------------------------------------------
__global__ __launch_bounds__(256) void k_agg(const ushort* __restrict__ hw,
                                             const float* __restrict__ dinv,
                                             const int* __restrict__ offsets,
                                             const int* __restrict__ csr_rows,
                                             const float* __restrict__ bias,
                                             float* __restrict__ out, int layer) {
    int node = blockIdx.x * 4 + (threadIdx.x >> 6);
    int lane = threadIdx.x & 63;
    int q = lane >> 4;
    int m = lane & 15;

    float acc[8] = {};
    int s = offsets[node], e = offsets[node + 1];
    int j = s + q;
    for (; j + 4 < e; j += 8) {
        int r0 = csr_rows[j];
        int r1 = csr_rows[j + 4];
        short8 v0 = *((const short8*)(hw + (size_t)r0 * D) + m);
        short8 v1 = *((const short8*)(hw + (size_t)r1 * D) + m);
        #pragma unroll
        for (int i = 0; i < 8; ++i)
            acc[i] += bf2f((ushort)v0[i]) + bf2f((ushort)v1[i]);
    }
    for (; j < e; j += 4) {
        int r = csr_rows[j];
        short8 v = *((const short8*)(hw + (size_t)r * D) + m);
        #pragma unroll
        for (int i = 0; i < 8; ++i) acc[i] += bf2f((ushort)v[i]);
    }
    // reduce across the 4 quarters (lanes with same m)
    #pragma unroll
    for (int i = 0; i < 8; ++i) {
        acc[i] += __shfl_xor(acc[i], 16);
        acc[i] += __shfl_xor(acc[i], 32);
    }

    if (q == 0) {
        float di = dinv[node];
        short8 sv = *((const short8*)(hw + (size_t)node * D) + m);
        float4 ba = ((const float4*)bias)[2 * m];
        float4 bb = ((const float4*)bias)[2 * m + 1];
        float bv[8] = {ba.x, ba.y, ba.z, ba.w, bb.x, bb.y, bb.z, bb.w};
        float o[8];
        #pragma unroll
        for (int i = 0; i < 8; ++i)
            o[i] = tanhf(di * (acc[i] + bf2f((ushort)sv[i])) + bv[i]);
        float* op = out + ((size_t)node * 3 + layer) * D;
        ((float4*)op)[2 * m]     = make_float4(o[0], o[1], o[2], o[3]);
        ((float4*)op)[2 * m + 1] = make_float4(o[4], o[5], o[6], o[7]);
    }
}

// ---------------------------------------------------------------------------

extern "C" void kernel_launch(void* const* d_in, const int* in_sizes, int n_in,
                              void* d_out, int out_size, void* d_ws, size_t ws_size,
                              hipStream_t stream) {
    const float* x  = (const float*)d_in[0];
    const int*   ei = (const int*)d_in[1];
    const float* W0 = (const float*)d_in[2];
    const float* b0 = (const float*)d_in[3];
    const float* W1 = (const float*)d_in[4];
    const float* b1 = (const float*)d_in[5];
    const float* W2 = (const float*)d_in[6];
    const float* b2 = (const float*)d_in[7];
    float* out = (float*)d_out;

    const int* row = ei;             // edge_index[0]
    const int* col = ei + N_EDGES;   // edge_index[1]

    // workspace layout (all segments 16B-aligned)
    float*  dinv    = (float*)d_ws;                // NPAD
    int*    counts  = (int*)(dinv + NPAD);         // NPAD
    int*    offsets = counts + NPAD;               // NPAD (N+1 used)
    int*    partials= offsets + NPAD;              // 256
    ushort* wt      = (ushort*)(partials + 256);   // 3*16384 bf16 (96 KB)
    int*    rank_buf= (int*)(wt + 3 * 16384);      // N_EDGES
    int*    csr     = rank_buf + N_EDGES;          // N_EDGES
    ushort* hw      = (ushort*)(csr + N_EDGES);    // NPAD*D bf16

    int nb_e8 = (N_EDGES / 8 + 255) / 256;         // 391

    hipMemsetAsync(counts, 0, NPAD * sizeof(int), stream);
    k_count_wconv<<<WCONV_BLKS + nb_e8, 256, 0, stream>>>(col, counts, rank_buf,
                                                          W0, W1, W2, wt);
    k_scan_local<<<NBLK, 256, 0, stream>>>(counts, offsets, partials);
    k_scan_add<<<NBLK, 256, 0, stream>>>(offsets, partials, counts, dinv);
    k_fill<<<nb_e8, 256, 0, stream>>>(row, col, offsets, rank_buf, csr);

    int nb_agg = N_NODES / 4;   // one wave per node

    const float* bs_[3] = {b0, b1, b2};
    for (int l = 0; l < 3; ++l) {
        const float* h = (l == 0) ? x : (out + (size_t)(l - 1) * D);
        int stride = (l == 0) ? D : 3 * D;
        k_gemm<<<NTILES, 256, 0, stream>>>(h, stride, wt + l * 16384, dinv, hw);
        k_agg<<<nb_agg, 256, 0, stream>>>(hw, dinv, offsets, csr, bs_[l], out, l);
    }
}

// Round 10
// 292.480 us; speedup vs baseline: 1.0691x; 1.0484x over previous
//
#include <hip/hip_runtime.h>
#include <math.h>

#define N_NODES 50000
#define N_EDGES 800000
#define D 128
#define NPAD 50048   // N rounded up, keeps segments 16B-aligned
#define NBLK 196     // ceil(N_NODES/256)

typedef unsigned int uint32;
typedef __attribute__((ext_vector_type(8))) short short8;   // 8 bf16 (4 VGPRs)
typedef __attribute__((ext_vector_type(4))) float f32x4;    // MFMA C/D

__device__ __forceinline__ ushort f2bf(float f) {
    uint32 u = __float_as_uint(f);
    u = (u + 0x7fff + ((u >> 16) & 1)) >> 16;   // round-to-nearest-even
    return (ushort)u;
}
__device__ __forceinline__ float bf2f(ushort u) {
    return __uint_as_float(((uint32)u) << 16);
}

// ---------------------------------------------------------------------------
// Fused: blocks 0..191 pre-convert W0/W1/W2 -> wt[l][n*128+k] (bf16, transposed)
//        blocks 192..  count edges (8/thread) + record per-edge rank
// ---------------------------------------------------------------------------
#define WCONV_BLKS 192

__global__ __launch_bounds__(256) void k_count_wconv(const int* __restrict__ col,
                                                     int* __restrict__ counts,
                                                     int* __restrict__ rank_buf,
                                                     const float* __restrict__ W0,
                                                     const float* __restrict__ W1,
                                                     const float* __restrict__ W2,
                                                     ushort* __restrict__ wt) {
    int tid = threadIdx.x;
    if (blockIdx.x < WCONV_BLKS) {
        int i = blockIdx.x * 256 + tid;    // 49152 total
        int l = i >> 14;
        int flat = i & 16383;
        int n = flat >> 7, k = flat & 127;
        const float* W = (l == 0) ? W0 : (l == 1) ? W1 : W2;
        wt[i] = f2bf(W[k * 128 + n]);
    } else {
        int i8 = ((blockIdx.x - WCONV_BLKS) * 256 + tid) * 8;
        if (i8 < N_EDGES) {   // N_EDGES % 8 == 0 -> all-or-nothing
            int4 c0 = *(const int4*)(col + i8);
            int4 c1 = *(const int4*)(col + i8 + 4);
            int4 r0, r1;
            r0.x = atomicAdd(&counts[c0.x], 1);
            r0.y = atomicAdd(&counts[c0.y], 1);
            r0.z = atomicAdd(&counts[c0.z], 1);
            r0.w = atomicAdd(&counts[c0.w], 1);
            r1.x = atomicAdd(&counts[c1.x], 1);
            r1.y = atomicAdd(&counts[c1.y], 1);
            r1.z = atomicAdd(&counts[c1.z], 1);
            r1.w = atomicAdd(&counts[c1.w], 1);
            *(int4*)(rank_buf + i8)     = r0;
            *(int4*)(rank_buf + i8 + 4) = r1;
        }
    }
}

// ---------------------------------------------------------------------------
// CSR scan: per-block local scan -> fused base-reduce + add + dinv
// ---------------------------------------------------------------------------

__global__ __launch_bounds__(256) void k_scan_local(const int* __restrict__ counts,
                                                    int* __restrict__ offsets,
                                                    int* __restrict__ partials) {
    __shared__ int wsum[4];
    int tid = threadIdx.x;
    int i = blockIdx.x * 256 + tid;
    int v = (i < N_NODES) ? counts[i] : 0;
    int lane = tid & 63, wv = tid >> 6;
    int x = v;
    #pragma unroll
    for (int off = 1; off < 64; off <<= 1) {
        int y = __shfl_up(x, off);
        if (lane >= off) x += y;
    }
    if (lane == 63) wsum[wv] = x;
    __syncthreads();
    int b0 = wsum[0], b1 = wsum[1], b2 = wsum[2], b3 = wsum[3];
    int base = (wv > 0 ? b0 : 0) + (wv > 1 ? b1 : 0) + (wv > 2 ? b2 : 0);
    if (i < N_NODES) offsets[i] = base + x - v;
    if (tid == 255) partials[blockIdx.x] = b0 + b1 + b2 + b3;
}

__global__ __launch_bounds__(256) void k_scan_add(int* __restrict__ offsets,
                                                  const int* __restrict__ partials,
                                                  const int* __restrict__ counts,
                                                  float* __restrict__ dinv) {
    __shared__ int wsum[4];
    int tid = threadIdx.x;
    int p = (tid < (int)blockIdx.x && tid < NBLK) ? partials[tid] : 0;
    int lane = tid & 63, wv = tid >> 6;
    #pragma unroll
    for (int off = 32; off; off >>= 1) p += __shfl_down(p, off);
    if (lane == 0) wsum[wv] = p;
    __syncthreads();
    int base = wsum[0] + wsum[1] + wsum[2] + wsum[3];
    int i = blockIdx.x * 256 + tid;
    if (i < N_NODES) {
        offsets[i] += base;
        dinv[i] = rsqrtf((float)counts[i] + 1.0f);  // +1 self-loop
    }
    if (i == 0) offsets[N_NODES] = N_EDGES;
}

__global__ __launch_bounds__(256) void k_fill(const int* __restrict__ row,
                                              const int* __restrict__ col,
                                              const int* __restrict__ offsets,
                                              const int* __restrict__ rank_buf,
                                              int* __restrict__ csr_rows) {
    int i8 = (blockIdx.x * 256 + threadIdx.x) * 8;
    if (i8 < N_EDGES) {
        int4 c0 = *(const int4*)(col + i8);
        int4 c1 = *(const int4*)(col + i8 + 4);
        int4 r0 = *(const int4*)(rank_buf + i8);
        int4 r1 = *(const int4*)(rank_buf + i8 + 4);
        int4 w0 = *(const int4*)(row + i8);
        int4 w1 = *(const int4*)(row + i8 + 4);
        csr_rows[offsets[c0.x] + r0.x] = w0.x;
        csr_rows[offsets[c0.y] + r0.y] = w0.y;
        csr_rows[offsets[c0.z] + r0.z] = w0.z;
        csr_rows[offsets[c0.w] + r0.w] = w0.w;
        csr_rows[offsets[c1.x] + r1.x] = w1.x;
        csr_rows[offsets[c1.y] + r1.y] = w1.y;
        csr_rows[offsets[c1.z] + r1.z] = w1.z;
        csr_rows[offsets[c1.w] + r1.w] = w1.w;
    }
}

// ---------------------------------------------------------------------------
// MFMA GEMM: hw_bf16[N,D] = bf16( dinv[.] * (h @ W) ), h fp32 with row stride
// (x: stride D; out: stride 3D). One 64-row tile per block, 4 waves x 16 rows.
// A staged to LDS with coalesced float4 reads + inline bf16 convert; Wt staged
// from pre-converted global bf16. One barrier per kernel.
// mfma_f32_16x16x32_bf16: A[m=lane&15][k=(lane>>4)*8+j];
// B[k=(lane>>4)*8+j][n=lane&15]; D col=lane&15, row=(lane>>4)*4+reg.
// ---------------------------------------------------------------------------
#define BM 64
#define LDA 136                          // padded ushort stride (272 B)
#define NTILES ((N_NODES + BM - 1) / BM) // 782

__global__ __launch_bounds__(256) void k_gemm(const float* __restrict__ h, int hstride,
                                              const ushort* __restrict__ wt,
                                              const float* __restrict__ dinv,
                                              ushort* __restrict__ hw) {
    __shared__ __align__(16) ushort Wt[D * LDA];    // 34.8 KB
    __shared__ __align__(16) ushort As[BM * LDA];   // 17.4 KB
    int tid = threadIdx.x;
    int lane = tid & 63;
    int w = tid >> 6;
    int quad = lane >> 4;
    int m16 = lane & 15;
    int row0 = blockIdx.x * BM;

    // stage Wt: 128 rows x 16 chunks of 8 bf16 (16B) = 2048 chunks, 8/thread
    #pragma unroll
    for (int i = 0; i < 8; ++i) {
        int chunk = i * 256 + tid;
        int n = chunk >> 4, k16 = chunk & 15;
        *(short8*)(Wt + n * LDA + k16 * 8) = *(const short8*)(wt + n * 128 + k16 * 8);
    }
    // stage A: 64 rows x 32 float4 = 2048 float4 chunks, 8/thread, coalesced
    #pragma unroll
    for (int p = 0; p < 8; ++p) {
        int flat = p * 256 + tid;
        int r = flat >> 5, c4 = flat & 31;
        int row = row0 + r;
        ushort4 u = {0, 0, 0, 0};
        if (row < N_NODES) {
            float4 v = *(const float4*)(h + (size_t)row * hstride + c4 * 4);
            u.x = f2bf(v.x); u.y = f2bf(v.y); u.z = f2bf(v.z); u.w = f2bf(v.w);
        }
        *(ushort4*)(As + r * LDA + c4 * 4) = u;
    }
    __syncthreads();   // only barrier

    f32x4 acc[8];
    #pragma unroll
    for (int ct = 0; ct < 8; ++ct) acc[ct] = (f32x4){0.f, 0.f, 0.f, 0.f};

    #pragma unroll
    for (int ks = 0; ks < 4; ++ks) {
        short8 a = *(const short8*)(As + (w * 16 + m16) * LDA + ks * 32 + quad * 8);
        #pragma unroll
        for (int ct = 0; ct < 8; ++ct) {
            short8 b = *(const short8*)(Wt + (ct * 16 + m16) * LDA + ks * 32 + quad * 8);
            acc[ct] = __builtin_amdgcn_mfma_f32_16x16x32_bf16(a, b, acc[ct], 0, 0, 0);
        }
    }

    // epilogue: dinv scale + bf16, transpose through the wave's OWN As rows
    float dv[4];
    #pragma unroll
    for (int r = 0; r < 4; ++r) {
        int row = row0 + w * 16 + quad * 4 + r;
        dv[r] = (row < N_NODES) ? dinv[row] : 0.f;
    }
    #pragma unroll
    for (int ct = 0; ct < 8; ++ct) {
        #pragma unroll
        for (int r = 0; r < 4; ++r)
            As[(w * 16 + quad * 4 + r) * LDA + ct * 16 + m16] = f2bf(acc[ct][r] * dv[r]);
    }
    // store 16 rows x 128 cols: 256 chunks of 8 elems (16B), 4 iters x 64 lanes
    #pragma unroll
    for (int i = 0; i < 4; ++i) {
        int chunk = i * 64 + lane;
        int r = chunk >> 4, c8 = chunk & 15;
        int row = row0 + w * 16 + r;
        if (row < N_NODES) {
            short8 v = *(const short8*)(As + (w * 16 + r) * LDA + c8 * 8);
            *(short8*)(hw + (size_t)row * D + c8 * 8) = v;
        }
    }
}

// ---------------------------------------------------------------------------
// Aggregate (bf16 rows): one 16-lane QUARTER per node (16 nodes / 256-thr
// block). Lane m owns cols 8m..8m+7 (short8, 16B). Quarter walks its node's
// edge list sequentially, unroll x4 -> 16 gather chains in flight per wave.
// No cross-lane reduction; epilogue runs on all 64 lanes.
// ---------------------------------------------------------------------------
__global__ __launch_bounds__(256) void k_agg(const ushort* __restrict__ hw,
                                             const float* __restrict__ dinv,
                                             const int* __restrict__ offsets,
                                             const int* __restrict__ csr_rows,
                                             const float* __restrict__ bias,
                                             float* __restrict__ out, int layer) {
    int tid = threadIdx.x;
    int node = blockIdx.x * 16 + (tid >> 4);   // 16 quarters per block
    int m = tid & 15;

    float acc[8] = {};
    int s = offsets[node], e = offsets[node + 1];
    int j = s;
    for (; j + 3 < e; j += 4) {
        int r0 = csr_rows[j];
        int r1 = csr_rows[j + 1];
        int r2 = csr_rows[j + 2];
        int r3 = csr_rows[j + 3];
        short8 v0 = *((const short8*)(hw + (size_t)r0 * D) + m);
        short8 v1 = *((const short8*)(hw + (size_t)r1 * D) + m);
        short8 v2 = *((const short8*)(hw + (size_t)r2 * D) + m);
        short8 v3 = *((const short8*)(hw + (size_t)r3 * D) + m);
        #pragma unroll
        for (int i = 0; i < 8; ++i)
            acc[i] += (bf2f((ushort)v0[i]) + bf2f((ushort)v1[i]))
                    + (bf2f((ushort)v2[i]) + bf2f((ushort)v3[i]));
    }
    for (; j < e; ++j) {
        int r = csr_rows[j];
        short8 v = *((const short8*)(hw + (size_t)r * D) + m);
        #pragma unroll
        for (int i = 0; i < 8; ++i) acc[i] += bf2f((ushort)v[i]);
    }

    float di = dinv[node];
    short8 sv = *((const short8*)(hw + (size_t)node * D) + m);
    float4 ba = ((const float4*)bias)[2 * m];
    float4 bb = ((const float4*)bias)[2 * m + 1];
    float bv[8] = {ba.x, ba.y, ba.z, ba.w, bb.x, bb.y, bb.z, bb.w};
    float o[8];
    #pragma unroll
    for (int i = 0; i < 8; ++i)
        o[i] = tanhf(di * (acc[i] + bf2f((ushort)sv[i])) + bv[i]);
    float* op = out + ((size_t)node * 3 + layer) * D;
    ((float4*)op)[2 * m]     = make_float4(o[0], o[1], o[2], o[3]);
    ((float4*)op)[2 * m + 1] = make_float4(o[4], o[5], o[6], o[7]);
}

// ---------------------------------------------------------------------------

extern "C" void kernel_launch(void* const* d_in, const int* in_sizes, int n_in,
                              void* d_out, int out_size, void* d_ws, size_t ws_size,
                              hipStream_t stream) {
    const float* x  = (const float*)d_in[0];
    const int*   ei = (const int*)d_in[1];
    const float* W0 = (const float*)d_in[2];
    const float* b0 = (const float*)d_in[3];
    const float* W1 = (const float*)d_in[4];
    const float* b1 = (const float*)d_in[5];
    const float* W2 = (const float*)d_in[6];
    const float* b2 = (const float*)d_in[7];
    float* out = (float*)d_out;

    const int* row = ei;             // edge_index[0]
    const int* col = ei + N_EDGES;   // edge_index[1]

    // workspace layout (all segments 16B-aligned)
    float*  dinv    = (float*)d_ws;                // NPAD
    int*    counts  = (int*)(dinv + NPAD);         // NPAD
    int*    offsets = counts + NPAD;               // NPAD (N+1 used)
    int*    partials= offsets + NPAD;              // 256
    ushort* wt      = (ushort*)(partials + 256);   // 3*16384 bf16 (96 KB)
    int*    rank_buf= (int*)(wt + 3 * 16384);      // N_EDGES
    int*    csr     = rank_buf + N_EDGES;          // N_EDGES
    ushort* hw      = (ushort*)(csr + N_EDGES);    // NPAD*D bf16

    int nb_e8 = (N_EDGES / 8 + 255) / 256;         // 391

    hipMemsetAsync(counts, 0, NPAD * sizeof(int), stream);
    k_count_wconv<<<WCONV_BLKS + nb_e8, 256, 0, stream>>>(col, counts, rank_buf,
                                                          W0, W1, W2, wt);
    k_scan_local<<<NBLK, 256, 0, stream>>>(counts, offsets, partials);
    k_scan_add<<<NBLK, 256, 0, stream>>>(offsets, partials, counts, dinv);
    k_fill<<<nb_e8, 256, 0, stream>>>(row, col, offsets, rank_buf, csr);

    int nb_agg = N_NODES / 16;   // 3125 blocks, one quarter-wave per node

    const float* bs_[3] = {b0, b1, b2};
    for (int l = 0; l < 3; ++l) {
        const float* h = (l == 0) ? x : (out + (size_t)(l - 1) * D);
        int stride = (l == 0) ? D : 3 * D;
        k_gemm<<<NTILES, 256, 0, stream>>>(h, stride, wt + l * 16384, dinv, hw);
        k_agg<<<nb_agg, 256, 0, stream>>>(hw, dinv, offsets, csr, bs_[l], out, l);
    }
}